// Round 9
// baseline (1684.698 us; speedup 1.0000x reference)
//
#include <hip/hip_runtime.h>
#include <hip/hip_bf16.h>
#include <hip/hip_fp16.h>
#include <stdint.h>

#define NTOK   8192
#define DM     2048
#define NEXP   8
#define HR     1024
#define HS     8192
#define ROWS_MAX 18432   // 16384 + 8*255 rounded up to 256
#define YT_MAX 72        // ROWS_MAX / 256

typedef _Float16 f16;
typedef f16  f16x8 __attribute__((ext_vector_type(8)));
typedef float f32x4 __attribute__((ext_vector_type(4)));

#define GLP(p) ((const __attribute__((address_space(1))) void*)(p))
#define LDP(p) ((__attribute__((address_space(3))) void*)(p))

static __device__ __forceinline__ float silu_f(float v) {
  return v / (1.0f + __expf(-v));
}

// bijective XCD-chunk swizzle (m204 form)
static __device__ __forceinline__ int xcd_swz(int bid, int nwg) {
  const int q = nwg >> 3, r = nwg & 7;
  const int x = bid & 7, i = bid >> 3;
  return (x < r ? x * (q + 1) : r * (q + 1) + (x - r) * q) + i;
}

// ---------------- conversion kernels ----------------

__global__ __launch_bounds__(256)
void conv_x_kernel(const float* __restrict__ in, f16* __restrict__ out, int n8) {
  const int i = blockIdx.x * 256 + threadIdx.x;
  if (i >= n8) return;
  const float4* p = (const float4*)in + (size_t)i * 2;
  const float4 a = p[0], b = p[1];
  f16x8 o;
  o[0] = (f16)a.x; o[1] = (f16)a.y; o[2] = (f16)a.z; o[3] = (f16)a.w;
  o[4] = (f16)b.x; o[5] = (f16)b.y; o[6] = (f16)b.z; o[7] = (f16)b.w;
  ((f16x8*)out)[i] = o;
}

// f32 [b][R][C] -> f16 [b][C][R] with optional 16-row g/u interleave.
// rmap==0: phys row = tr.  rmap==1 (g) / 2 (u): phys = ((tr>>4)<<5)+((rmap-1)<<4)+(tr&15)
__global__ __launch_bounds__(256)
void conv_t_kernel(const float* __restrict__ in, f16* __restrict__ out,
                   int R, int C, size_t ostride, int rmap) {
  __shared__ float t[32][33];
  const int b = blockIdx.z;
  const float* inb = in + (size_t)b * R * C;
  f16* outb = out + (size_t)b * ostride;
  const int c0 = blockIdx.x * 32, r0 = blockIdx.y * 32;
  const int tx = threadIdx.x, ty0 = threadIdx.y;
#pragma unroll
  for (int yy = 0; yy < 4; ++yy) {
    const int ty = ty0 + yy * 8;
    t[ty][tx] = inb[(size_t)(r0 + ty) * C + (c0 + tx)];
  }
  __syncthreads();
#pragma unroll
  for (int yy = 0; yy < 4; ++yy) {
    const int ty = ty0 + yy * 8;
    const int tr = c0 + ty;
    const int pr = rmap ? (((tr >> 4) << 5) + ((rmap - 1) << 4) + (tr & 15)) : tr;
    outb[(size_t)pr * R + (r0 + tx)] = (f16)t[tx][ty];
  }
}

// ---------------- gating ----------------

__global__ __launch_bounds__(256)
void gate_kernel(const float* __restrict__ x, const float* __restrict__ wgate,
                 float* __restrict__ gateW, int* __restrict__ gateI,
                 float* __restrict__ importance, int* __restrict__ cnt) {
  __shared__ float impl[NEXP];
  __shared__ int cntl[NEXP];
  const int tid = threadIdx.x, lane = tid & 63, wid = tid >> 6;
  if (tid < NEXP) { impl[tid] = 0.f; cntl[tid] = 0; }
  __syncthreads();
  for (int s = 0; s < 8; ++s) {
    const int t = blockIdx.x * 32 + wid * 8 + s;
    const float* xr = x + (size_t)t * DM;
    float pv[NEXP] = {0.f, 0.f, 0.f, 0.f, 0.f, 0.f, 0.f, 0.f};
    for (int j = 0; j < DM / 64; ++j) {
      const int c = lane + j * 64;
      const float xv = xr[c];
#pragma unroll
      for (int e = 0; e < NEXP; ++e) pv[e] += xv * wgate[e * DM + c];
    }
#pragma unroll
    for (int e = 0; e < NEXP; ++e) {
#pragma unroll
      for (int st = 32; st >= 1; st >>= 1) pv[e] += __shfl_xor(pv[e], st);
    }
    if (lane == 0) {
      float v1 = pv[0]; int i1 = 0;
#pragma unroll
      for (int e = 1; e < NEXP; ++e) if (pv[e] > v1) { v1 = pv[e]; i1 = e; }
      float v2 = -1e30f; int i2 = 0;
#pragma unroll
      for (int e = 0; e < NEXP; ++e) if (e != i1 && pv[e] > v2) { v2 = pv[e]; i2 = e; }
      const float g1 = 1.f / (1.f + expf(v2 - v1));
      gateW[t * 2 + 0] = g1;  gateW[t * 2 + 1] = 1.f - g1;
      gateI[t * 2 + 0] = i1;  gateI[t * 2 + 1] = i2;
      float mx = pv[0];
#pragma unroll
      for (int e = 1; e < NEXP; ++e) mx = fmaxf(mx, pv[e]);
      float sum = 0.f, ex[NEXP];
#pragma unroll
      for (int e = 0; e < NEXP; ++e) { ex[e] = expf(pv[e] - mx); sum += ex[e]; }
      const float inv = 1.f / sum;
#pragma unroll
      for (int e = 0; e < NEXP; ++e) atomicAdd(&impl[e], ex[e] * inv);
      atomicAdd(&cntl[i1], 1);
      atomicAdd(&cntl[i2], 1);
    }
  }
  __syncthreads();
  if (tid < NEXP) {
    atomicAdd(&importance[tid], impl[tid]);
    atomicAdd(&cnt[tid], cntl[tid]);
  }
}

__global__ void scan_kernel(const int* __restrict__ cnt, int* __restrict__ seg,
                            int* __restrict__ cursor, const float* __restrict__ imp,
                            float* __restrict__ lb_out) {
  if (threadIdx.x == 0 && blockIdx.x == 0) {
    int o = 0;
#pragma unroll
    for (int e = 0; e < NEXP; ++e) {
      seg[e] = o;
      o += (cnt[e] + 255) & ~255;
      cursor[e] = 0;
    }
    seg[NEXP] = o;
    float s = 0.f;
#pragma unroll
    for (int e = 0; e < NEXP; ++e) {
      const float ce = imp[e] * ((float)NEXP / (float)NTOK);
      s += ce * ce;
    }
    *lb_out = s / (float)NEXP;
  }
}

__global__ __launch_bounds__(256)
void scatter_kernel(const float* __restrict__ gateW, const int* __restrict__ gateI,
                    const int* __restrict__ seg, int* __restrict__ cursor,
                    int* __restrict__ rowtok, float* __restrict__ rowgate) {
  const int t = blockIdx.x * 256 + threadIdx.x;
  const int lane = threadIdx.x & 63;
#pragma unroll
  for (int k = 0; k < 2; ++k) {
    const int e = gateI[t * 2 + k];
    const float g = gateW[t * 2 + k];
    for (int ee = 0; ee < NEXP; ++ee) {
      const unsigned long long m = __ballot(e == ee);
      if (e == ee) {
        const int leader = __ffsll((unsigned long long)m) - 1;
        const int rank = (int)__popcll(m & ((1ull << lane) - 1ull));
        int base = 0;
        if (lane == leader) base = atomicAdd(&cursor[ee], (int)__popcll(m));
        base = __shfl(base, leader);
        const int pos = seg[ee] + base + rank;
        rowtok[pos] = t;
        rowgate[pos] = g;
      }
    }
  }
}

// ---------------- 256x256 GEMM, BK=64, dbuf LDS, T2 read-swizzle ----------------
// (R6-exact mainloop — best measured: 963 TF effective, MfmaUtil 44%.)
// A: [M][K] row-major f16.  B: transposed [N][K] row-major f16.
// LDS tile: logical [256][64] f16, byte ^= ((row&7)<<4); global_load_lds writes
// LINEAR, inverse swizzle pre-applied to per-lane GLOBAL source (rule #21).
// One barrier per K-tile: stage(next) issued FIRST, full-tile compute, then
// vmcnt(0)+__syncthreads (loads get the whole iteration to land).
// NOTE (R4/R7 lessons): partial 8-phase / counted-vmcnt ports both REGRESSED
// (m131/m141 failure mode). Do not re-attempt without a verified full ledger.

struct G8Ptrs { const f16* a[4]; const f16* b[4]; };

// thread's i-th staging instr: linear LDS byte L -> logical (row r, col c)
static __device__ __forceinline__ void swz_rc(int tid, int i, int& r, int& c) {
  const int L = i * 8192 + tid * 16;
  const int U = L ^ (((L >> 7) & 7) << 4);
  r = U >> 7;
  c = (U & 127) >> 1;
}

static __device__ __forceinline__ void stage8(const G8Ptrs& P, int koff,
                                              f16* AsB, f16* BsB, int wid) {
#pragma unroll
  for (int i = 0; i < 4; ++i) {
    __builtin_amdgcn_global_load_lds(GLP(P.a[i] + koff), LDP(AsB + i * 4096 + wid * 512), 16, 0, 0);
    __builtin_amdgcn_global_load_lds(GLP(P.b[i] + koff), LDP(BsB + i * 4096 + wid * 512), 16, 0, 0);
  }
}

static __device__ __forceinline__ void g8_mainloop(const G8Ptrs& P, int nt,
                                                   f16* As, f16* Bs,
                                                   f32x4 (&acc)[8][4]) {
  const int tid = threadIdx.x;
  const int lane = tid & 63, wid = tid >> 6;
  const int wr = wid >> 2, wc = wid & 3;
  const int fr = lane & 15, fk = (lane >> 4) * 8;

  stage8(P, 0, As, Bs, wid);
  asm volatile("s_waitcnt vmcnt(0)" ::: "memory");
  __syncthreads();

  for (int t = 0; t < nt; ++t) {
    const int cur = t & 1;
    if (t + 1 < nt)
      stage8(P, (t + 1) * 64, As + (cur ^ 1) * 16384, Bs + (cur ^ 1) * 16384, wid);
    const f16* Ab = As + cur * 16384;
    const f16* Bb = Bs + cur * 16384;
    f16x8 bf[4][2];
#pragma unroll
    for (int n = 0; n < 4; ++n) {
      const int r = wc * 64 + n * 16 + fr;
      const int sw = (r & 7) << 3;
#pragma unroll
      for (int ks = 0; ks < 2; ++ks)
        bf[n][ks] = *(const f16x8*)&Bb[(r * 64 + ks * 32 + fk) ^ sw];
    }
#pragma unroll
    for (int mh = 0; mh < 2; ++mh) {
#pragma unroll
      for (int ks = 0; ks < 2; ++ks) {
        f16x8 af[4];
#pragma unroll
        for (int m = 0; m < 4; ++m) {
          const int r = wr * 128 + (mh * 4 + m) * 16 + fr;
          af[m] = *(const f16x8*)&Ab[(r * 64 + ks * 32 + fk) ^ ((r & 7) << 3)];
        }
#pragma unroll
        for (int m = 0; m < 4; ++m)
#pragma unroll
          for (int n = 0; n < 4; ++n)
            acc[mh * 4 + m][n] =
                __builtin_amdgcn_mfma_f32_16x16x32_f16(af[m], bf[n][ks], acc[mh * 4 + m][n], 0, 0, 0);
      }
    }
    asm volatile("s_waitcnt vmcnt(0)" ::: "memory");
    __syncthreads();
  }
}

// expert for padded global row r0: seg[e] <= r0 < seg[e+1]
static __device__ __forceinline__ int seg_lookup(const int* __restrict__ seg, int r0) {
  int e = 0;
#pragma unroll
  for (int k = 1; k < NEXP; ++k) if (r0 >= seg[k]) e = k;
  return e;
}

// ---- merged gate|up (+silu): shared blocks [0,2048) + routed blocks [2048,2624) ----
// Both roles: K=DM, B 16-col g/u interleaved, epilogue h=silu(g)*u.
__global__ __launch_bounds__(512, 2)
void g8_gu_all(const f16* __restrict__ x16, const f16* __restrict__ SguI,
               f16* __restrict__ hbuf, const f16* __restrict__ Wgu,
               f16* __restrict__ hr, const int* __restrict__ rowtok,
               const int* __restrict__ seg) {
  __shared__ f16 As[2 * 16384], Bs[2 * 16384];
  const int tid = threadIdx.x;
  G8Ptrs P;
  f16* H;
  int Nh, row0, n0;
  if (blockIdx.x < 2048) {
    const int lin = xcd_swz(blockIdx.x, 2048);
    row0 = (lin & 31) * 256;        // gx=32, M fastest: share B tile
    n0 = (lin >> 5) * 256;
#pragma unroll
    for (int i = 0; i < 4; ++i) {
      int r, c; swz_rc(tid, i, r, c);
      P.a[i] = x16 + (size_t)(row0 + r) * DM + c;
      P.b[i] = SguI + (size_t)(n0 + r) * DM + c;
    }
    H = hbuf; Nh = HS;
  } else {
    const int rb = blockIdx.x - 2048;
    n0 = (rb & 7) * 256;
    row0 = (rb >> 3) * 256;
    if (row0 >= seg[NEXP]) return;
    const int e = seg_lookup(seg, row0);
    const f16* Bbase = Wgu + (size_t)e * 2048 * DM;
#pragma unroll
    for (int i = 0; i < 4; ++i) {
      int r, c; swz_rc(tid, i, r, c);
      int tok = rowtok[row0 + r];
      if (tok < 0) tok = 0;   // pad rows: junk, discarded downstream
      P.a[i] = x16 + (size_t)tok * DM + c;
      P.b[i] = Bbase + (size_t)(n0 + r) * DM + c;
    }
    H = hr; Nh = HR;
  }
  f32x4 acc[8][4] = {};
  g8_mainloop(P, DM / 64, As, Bs, acc);
  const int lane = tid & 63, wid = tid >> 6;
  const int wr = wid >> 2, wc = wid & 3;
  const int fr = lane & 15, r0v = (lane >> 4) * 4;
  const int hc0 = (n0 + wc * 64) >> 1;
#pragma unroll
  for (int m = 0; m < 8; ++m)
#pragma unroll
    for (int k = 0; k < 2; ++k)
#pragma unroll
      for (int rr = 0; rr < 4; ++rr) {
        const int row = row0 + wr * 128 + m * 16 + r0v + rr;
        const int hcol = hc0 + k * 16 + fr;
        const float g = acc[m][2 * k][rr];
        const float u = acc[m][2 * k + 1][rr];
        H[(size_t)row * Nh + hcol] = (f16)(silu_f(g) * u);
      }
}

// ---- merged down: shared blocks [0,256) + routed blocks [256,832) ----
// out pre-zeroed; BOTH roles accumulate via atomicAdd (unordered within dispatch).
__global__ __launch_bounds__(512, 2)
void g8_down_all(const f16* __restrict__ hbuf, const f16* __restrict__ SdT,
                 const f16* __restrict__ hr, const f16* __restrict__ WdT,
                 float* __restrict__ out, const int* __restrict__ seg,
                 const int* __restrict__ rowtok, const float* __restrict__ rowgate) {
  __shared__ f16 As[2 * 16384], Bs[2 * 16384];
  const int tid = threadIdx.x;
  G8Ptrs P;
  int row0, n0, nt;
  bool routed;
  if (blockIdx.x < 256) {
    const int lin = xcd_swz(blockIdx.x, 256);
    row0 = (lin & 31) * 256;        // 32 M-tiles x 8 N-tiles
    n0 = (lin >> 5) * 256;
#pragma unroll
    for (int i = 0; i < 4; ++i) {
      int r, c; swz_rc(tid, i, r, c);
      P.a[i] = hbuf + (size_t)(row0 + r) * HS + c;
      P.b[i] = SdT + (size_t)(n0 + r) * HS + c;
    }
    nt = HS / 64; routed = false;
  } else {
    const int rb = blockIdx.x - 256;
    n0 = (rb & 7) * 256;
    row0 = (rb >> 3) * 256;
    if (row0 >= seg[NEXP]) return;
    const int e = seg_lookup(seg, row0);
    const f16* Bbase = WdT + (size_t)e * DM * HR;
#pragma unroll
    for (int i = 0; i < 4; ++i) {
      int r, c; swz_rc(tid, i, r, c);
      P.a[i] = hr + (size_t)(row0 + r) * HR + c;
      P.b[i] = Bbase + (size_t)(n0 + r) * HR + c;
    }
    nt = HR / 64; routed = true;
  }
  f32x4 acc[8][4] = {};
  g8_mainloop(P, nt, As, Bs, acc);
  const int lane = tid & 63, wid = tid >> 6;
  const int wr = wid >> 2, wc = wid & 3;
  const int fr = lane & 15, r0v = (lane >> 4) * 4;
  if (!routed) {
#pragma unroll
    for (int m = 0; m < 8; ++m)
#pragma unroll
      for (int n = 0; n < 4; ++n)
#pragma unroll
        for (int rr = 0; rr < 4; ++rr) {
          const int row = row0 + wr * 128 + m * 16 + r0v + rr;
          const int col = n0 + wc * 64 + n * 16 + fr;
          atomicAdd(&out[(size_t)row * DM + col], acc[m][n][rr]);
        }
  } else {
#pragma unroll
    for (int m = 0; m < 8; ++m)
#pragma unroll
      for (int rr = 0; rr < 4; ++rr) {
        const int pos = row0 + wr * 128 + m * 16 + r0v + rr;
        const int tok = rowtok[pos];
        if (tok >= 0) {
          const float gw = rowgate[pos];
#pragma unroll
          for (int n = 0; n < 4; ++n) {
            const int col = n0 + wc * 64 + n * 16 + fr;
            atomicAdd(&out[(size_t)tok * DM + col], acc[m][n][rr] * gw);
          }
        }
      }
  }
}

// ---------------- host ----------------

extern "C" void kernel_launch(void* const* d_in, const int* in_sizes, int n_in,
                              void* d_out, int out_size, void* d_ws, size_t ws_size,
                              hipStream_t stream) {
  const float* x  = (const float*)d_in[0];
  const float* wg = (const float*)d_in[1];
  const float* Wg = (const float*)d_in[2];
  const float* Wu = (const float*)d_in[3];
  const float* Wd = (const float*)d_in[4];
  const float* Sg = (const float*)d_in[5];
  const float* Su = (const float*)d_in[6];
  const float* Sd = (const float*)d_in[7];
  float* out = (float*)d_out;

  char* p = (char*)d_ws;
  auto take = [&](size_t b) { char* q = p; p += (b + 255) & ~(size_t)255; return q; };
  float* importance = (float*)take(32);
  int*   cnt        = (int*)take(32);
  int*   cursor     = (int*)take(32);
  int*   seg        = (int*)take(64);
  int*   rowtok     = (int*)take((size_t)ROWS_MAX * 4);
  float* rowgate    = (float*)take((size_t)ROWS_MAX * 4);
  float* gateW      = (float*)take((size_t)NTOK * 2 * 4);
  int*   gateI      = (int*)take((size_t)NTOK * 2 * 4);
  f16* x16   = (f16*)take((size_t)NTOK * DM * 2);
  f16* SguI  = (f16*)take((size_t)2 * HS * DM * 2);       // [16384][2048] g/u 16-interleaved
  f16* SdT   = (f16*)take((size_t)DM * HS * 2);           // [2048][8192]
  f16* WguI  = (f16*)take((size_t)NEXP * 2048 * DM * 2);  // [e][2048][2048] interleaved
  f16* WdT   = (f16*)take((size_t)NEXP * DM * HR * 2);    // [e][2048][1024]
  f16* hbuf  = (f16*)take((size_t)NTOK * HS * 2);         // h for all 8192 tokens (128 MB)
  f16* hr    = (f16*)take((size_t)ROWS_MAX * HR * 2);     // routed h
  if ((size_t)(p - (char*)d_ws) > ws_size) return;  // ws too small -> loud fail

  hipMemsetAsync(out, 0, (size_t)out_size * 4, stream);       // both down roles accumulate
  hipMemsetAsync(importance, 0, 768, stream);                 // importance+cnt+cursor
  hipMemsetAsync(rowtok, 0xFF, (size_t)ROWS_MAX * 4, stream); // -1

  conv_x_kernel<<<(NTOK * DM / 8 + 255) / 256, 256, 0, stream>>>(x, x16, NTOK * DM / 8);
  dim3 tb(32, 8);
  conv_t_kernel<<<dim3(HS / 32, DM / 32, 1), tb, 0, stream>>>(Sg, SguI, DM, HS, 0, 1);
  conv_t_kernel<<<dim3(HS / 32, DM / 32, 1), tb, 0, stream>>>(Su, SguI, DM, HS, 0, 2);
  conv_t_kernel<<<dim3(DM / 32, HS / 32, 1), tb, 0, stream>>>(Sd, SdT, HS, DM, 0, 0);
  conv_t_kernel<<<dim3(HR / 32, DM / 32, NEXP), tb, 0, stream>>>(Wg, WguI, DM, HR, (size_t)2048 * DM, 1);
  conv_t_kernel<<<dim3(HR / 32, DM / 32, NEXP), tb, 0, stream>>>(Wu, WguI, DM, HR, (size_t)2048 * DM, 2);
  conv_t_kernel<<<dim3(DM / 32, HR / 32, NEXP), tb, 0, stream>>>(Wd, WdT, HR, DM, (size_t)DM * HR, 0);

  gate_kernel<<<NTOK / 32, 256, 0, stream>>>(x, wg, gateW, gateI, importance, cnt);
  scan_kernel<<<1, 64, 0, stream>>>(cnt, seg, cursor, importance, out + (size_t)NTOK * DM);
  scatter_kernel<<<NTOK / 256, 256, 0, stream>>>(gateW, gateI, seg, cursor, rowtok, rowgate);

  // merged gate|up (+silu): shared 2048 blocks + routed 8n x 72y blocks
  g8_gu_all<<<2048 + 8 * YT_MAX, 512, 0, stream>>>(x16, SguI, hbuf, WguI, hr, rowtok, seg);

  // merged down: shared 256 blocks + routed 8n x 72y blocks (atomic accumulate)
  g8_down_all<<<256 + 8 * YT_MAX, 512, 0, stream>>>(hbuf, SdT, hr, WdT, out, seg, rowtok, rowgate);
}

// Round 10
// 1413.990 us; speedup vs baseline: 1.1914x; 1.1914x over previous
//
#include <hip/hip_runtime.h>
#include <hip/hip_bf16.h>
#include <hip/hip_fp16.h>
#include <stdint.h>

#define NTOK   8192
#define DM     2048
#define NEXP   8
#define HR     1024
#define HS     8192
#define ROWS_MAX 18432   // 16384 + 8*255 rounded up to 256

typedef _Float16 f16;
typedef f16  f16x8 __attribute__((ext_vector_type(8)));
typedef float f32x4 __attribute__((ext_vector_type(4)));

#define GLP(p) ((const __attribute__((address_space(1))) void*)(p))
#define LDP(p) ((__attribute__((address_space(3))) void*)(p))

static __device__ __forceinline__ float silu_f(float v) {
  return v / (1.0f + __expf(-v));
}

// bijective XCD-chunk swizzle (m204 form)
static __device__ __forceinline__ int xcd_swz(int bid, int nwg) {
  const int q = nwg >> 3, r = nwg & 7;
  const int x = bid & 7, i = bid >> 3;
  return (x < r ? x * (q + 1) : r * (q + 1) + (x - r) * q) + i;
}

// ---------------- unified weight transpose/convert (one dispatch) ----------------
// 6 segments x 16384 tiles of 32x32. f32 [R][C] -> f16 [C][R], optional 16-row
// g/u interleave (rmap 1=g, 2=u: phys row = ((tr>>4)<<5)+((rmap-1)<<4)+(tr&15)).

__global__ __launch_bounds__(256)
void conv_all_kernel(const float* __restrict__ Sg, const float* __restrict__ Su,
                     const float* __restrict__ Sd, const float* __restrict__ Wg,
                     const float* __restrict__ Wu, const float* __restrict__ Wd,
                     f16* __restrict__ SguI, f16* __restrict__ SdT,
                     f16* __restrict__ WguI, f16* __restrict__ WdT) {
  __shared__ float t[32][33];
  const int bid = blockIdx.x;
  const int s = bid >> 14, rr = bid & 16383;
  const float* in;
  f16* outb;
  int C, xbits, rmap;
  int b = 0, tile = rr;
  if (s >= 3) { b = rr >> 11; tile = rr & 2047; }
  switch (s) {
    case 0:  in = Sg; outb = SguI; C = HS; xbits = 8; rmap = 1; break;  // [2048][8192]
    case 1:  in = Su; outb = SguI; C = HS; xbits = 8; rmap = 2; break;
    case 2:  in = Sd; outb = SdT;  C = DM; xbits = 6; rmap = 0; break;  // [8192][2048]
    case 3:  in = Wg + (size_t)b * DM * HR; outb = WguI + (size_t)b * 2048 * DM;
             C = HR; xbits = 5; rmap = 1; break;                        // [2048][1024]
    case 4:  in = Wu + (size_t)b * DM * HR; outb = WguI + (size_t)b * 2048 * DM;
             C = HR; xbits = 5; rmap = 2; break;
    default: in = Wd + (size_t)b * HR * DM; outb = WdT + (size_t)b * DM * HR;
             C = DM; xbits = 6; rmap = 0; break;                        // [1024][2048]
  }
  const int c0 = (tile & ((1 << xbits) - 1)) << 5;
  const int r0 = (tile >> xbits) << 5;
  const int R_out = C;  // out leading dim = R of input; we only need C and row count via r0
  const int tx = threadIdx.x, ty0 = threadIdx.y;
#pragma unroll
  for (int yy = 0; yy < 4; ++yy) {
    const int ty = ty0 + yy * 8;
    t[ty][tx] = in[(size_t)(r0 + ty) * C + (c0 + tx)];
  }
  __syncthreads();
  // out row length = R (input rows). R = (s==2) ? HS : (s==5 ? HR : DM)
  const int R = (s == 2) ? HS : ((s == 5) ? HR : DM);
  (void)R_out;
#pragma unroll
  for (int yy = 0; yy < 4; ++yy) {
    const int ty = ty0 + yy * 8;
    const int tr = c0 + ty;
    const int pr = rmap ? (((tr >> 4) << 5) + ((rmap - 1) << 4) + (tr & 15)) : tr;
    outb[(size_t)pr * R + (r0 + tx)] = (f16)t[tx][ty];
  }
}

// ---------------- gating (+ fused x -> f16 conversion) ----------------

__global__ __launch_bounds__(256)
void gate_kernel(const float* __restrict__ x, const float* __restrict__ wgate,
                 f16* __restrict__ x16, float* __restrict__ gateW,
                 int* __restrict__ gateI, float* __restrict__ importance,
                 int* __restrict__ cnt) {
  __shared__ float impl[NEXP];
  __shared__ int cntl[NEXP];
  const int tid = threadIdx.x, lane = tid & 63, wid = tid >> 6;
  if (tid < NEXP) { impl[tid] = 0.f; cntl[tid] = 0; }
  __syncthreads();
  for (int s = 0; s < 8; ++s) {
    const int t = blockIdx.x * 32 + wid * 8 + s;
    const float* xr = x + (size_t)t * DM;
    f16* x16r = x16 + (size_t)t * DM;
    float pv[NEXP] = {0.f, 0.f, 0.f, 0.f, 0.f, 0.f, 0.f, 0.f};
    for (int j = 0; j < DM / 64; ++j) {
      const int c = lane + j * 64;
      const float xv = xr[c];
      x16r[c] = (f16)xv;   // fused conversion
#pragma unroll
      for (int e = 0; e < NEXP; ++e) pv[e] += xv * wgate[e * DM + c];
    }
#pragma unroll
    for (int e = 0; e < NEXP; ++e) {
#pragma unroll
      for (int st = 32; st >= 1; st >>= 1) pv[e] += __shfl_xor(pv[e], st);
    }
    if (lane == 0) {
      float v1 = pv[0]; int i1 = 0;
#pragma unroll
      for (int e = 1; e < NEXP; ++e) if (pv[e] > v1) { v1 = pv[e]; i1 = e; }
      float v2 = -1e30f; int i2 = 0;
#pragma unroll
      for (int e = 0; e < NEXP; ++e) if (e != i1 && pv[e] > v2) { v2 = pv[e]; i2 = e; }
      const float g1 = 1.f / (1.f + expf(v2 - v1));
      gateW[t * 2 + 0] = g1;  gateW[t * 2 + 1] = 1.f - g1;
      gateI[t * 2 + 0] = i1;  gateI[t * 2 + 1] = i2;
      float mx = pv[0];
#pragma unroll
      for (int e = 1; e < NEXP; ++e) mx = fmaxf(mx, pv[e]);
      float sum = 0.f, ex[NEXP];
#pragma unroll
      for (int e = 0; e < NEXP; ++e) { ex[e] = expf(pv[e] - mx); sum += ex[e]; }
      const float inv = 1.f / sum;
#pragma unroll
      for (int e = 0; e < NEXP; ++e) atomicAdd(&impl[e], ex[e] * inv);
      atomicAdd(&cntl[i1], 1);
      atomicAdd(&cntl[i2], 1);
    }
  }
  __syncthreads();
  if (tid < NEXP) {
    atomicAdd(&importance[tid], impl[tid]);
    atomicAdd(&cnt[tid], cntl[tid]);
  }
}

__global__ void scan_kernel(const int* __restrict__ cnt, int* __restrict__ seg,
                            int* __restrict__ cursor, const float* __restrict__ imp,
                            float* __restrict__ lb_out) {
  if (threadIdx.x == 0 && blockIdx.x == 0) {
    int o = 0;
#pragma unroll
    for (int e = 0; e < NEXP; ++e) {
      seg[e] = o;
      o += (cnt[e] + 255) & ~255;
      cursor[e] = 0;
    }
    seg[NEXP] = o;
    float s = 0.f;
#pragma unroll
    for (int e = 0; e < NEXP; ++e) {
      const float ce = imp[e] * ((float)NEXP / (float)NTOK);
      s += ce * ce;
    }
    *lb_out = s / (float)NEXP;
  }
}

__global__ __launch_bounds__(256)
void scatter_kernel(const float* __restrict__ gateW, const int* __restrict__ gateI,
                    const int* __restrict__ seg, int* __restrict__ cursor,
                    int* __restrict__ rowtok, float* __restrict__ rowgate) {
  const int t = blockIdx.x * 256 + threadIdx.x;
  const int lane = threadIdx.x & 63;
#pragma unroll
  for (int k = 0; k < 2; ++k) {
    const int e = gateI[t * 2 + k];
    const float g = gateW[t * 2 + k];
    for (int ee = 0; ee < NEXP; ++ee) {
      const unsigned long long m = __ballot(e == ee);
      if (e == ee) {
        const int leader = __ffsll((unsigned long long)m) - 1;
        const int rank = (int)__popcll(m & ((1ull << lane) - 1ull));
        int base = 0;
        if (lane == leader) base = atomicAdd(&cursor[ee], (int)__popcll(m));
        base = __shfl(base, leader);
        const int pos = seg[ee] + base + rank;
        rowtok[pos] = t;
        rowgate[pos] = g;
      }
    }
  }
}

// ---------------- 256x256 GEMM, BK=64, dbuf LDS, T2 read-swizzle ----------------
// (R6-exact mainloop — best measured: 963 TF effective, MfmaUtil 44%.)
// A: [M][K] row-major f16.  B: transposed [N][K] row-major f16.
// LDS tile: logical [256][64] f16, byte ^= ((row&7)<<4); global_load_lds writes
// LINEAR, inverse swizzle pre-applied to per-lane GLOBAL source (rule #21).
// One barrier per K-tile: stage(next) issued FIRST, full-tile compute, then
// vmcnt(0)+__syncthreads (loads get the whole iteration to land).
// NOTE (R4/R7/R9 lessons): partial 8-phase / counted-vmcnt ports and merged
// heterogeneous dispatches all REGRESSED. Keep this structure.

struct G8Ptrs { const f16* a[4]; const f16* b[4]; };

// thread's i-th staging instr: linear LDS byte L -> logical (row r, col c)
static __device__ __forceinline__ void swz_rc(int tid, int i, int& r, int& c) {
  const int L = i * 8192 + tid * 16;
  const int U = L ^ (((L >> 7) & 7) << 4);
  r = U >> 7;
  c = (U & 127) >> 1;
}

static __device__ __forceinline__ void stage8(const G8Ptrs& P, int koff,
                                              f16* AsB, f16* BsB, int wid) {
#pragma unroll
  for (int i = 0; i < 4; ++i) {
    __builtin_amdgcn_global_load_lds(GLP(P.a[i] + koff), LDP(AsB + i * 4096 + wid * 512), 16, 0, 0);
    __builtin_amdgcn_global_load_lds(GLP(P.b[i] + koff), LDP(BsB + i * 4096 + wid * 512), 16, 0, 0);
  }
}

static __device__ __forceinline__ void g8_mainloop(const G8Ptrs& P, int nt,
                                                   f16* As, f16* Bs,
                                                   f32x4 (&acc)[8][4]) {
  const int tid = threadIdx.x;
  const int lane = tid & 63, wid = tid >> 6;
  const int wr = wid >> 2, wc = wid & 3;
  const int fr = lane & 15, fk = (lane >> 4) * 8;

  stage8(P, 0, As, Bs, wid);
  asm volatile("s_waitcnt vmcnt(0)" ::: "memory");
  __syncthreads();

  for (int t = 0; t < nt; ++t) {
    const int cur = t & 1;
    if (t + 1 < nt)
      stage8(P, (t + 1) * 64, As + (cur ^ 1) * 16384, Bs + (cur ^ 1) * 16384, wid);
    const f16* Ab = As + cur * 16384;
    const f16* Bb = Bs + cur * 16384;
    f16x8 bf[4][2];
#pragma unroll
    for (int n = 0; n < 4; ++n) {
      const int r = wc * 64 + n * 16 + fr;
      const int sw = (r & 7) << 3;
#pragma unroll
      for (int ks = 0; ks < 2; ++ks)
        bf[n][ks] = *(const f16x8*)&Bb[(r * 64 + ks * 32 + fk) ^ sw];
    }
#pragma unroll
    for (int mh = 0; mh < 2; ++mh) {
#pragma unroll
      for (int ks = 0; ks < 2; ++ks) {
        f16x8 af[4];
#pragma unroll
        for (int m = 0; m < 4; ++m) {
          const int r = wr * 128 + (mh * 4 + m) * 16 + fr;
          af[m] = *(const f16x8*)&Ab[(r * 64 + ks * 32 + fk) ^ ((r & 7) << 3)];
        }
#pragma unroll
        for (int m = 0; m < 4; ++m)
#pragma unroll
          for (int n = 0; n < 4; ++n)
            acc[mh * 4 + m][n] =
                __builtin_amdgcn_mfma_f32_16x16x32_f16(af[m], bf[n][ks], acc[mh * 4 + m][n], 0, 0, 0);
      }
    }
    asm volatile("s_waitcnt vmcnt(0)" ::: "memory");
    __syncthreads();
  }
}

// fused gate|up GEMM + silu epilogue -> f16 H (B 16-col g/u interleaved)
__global__ __launch_bounds__(512, 2)
void g8_gu(const f16* __restrict__ A, const f16* __restrict__ B,
           f16* __restrict__ H, int gx, int Nh, int K) {
  __shared__ f16 As[2 * 16384], Bs[2 * 16384];
  const int lin = xcd_swz(blockIdx.x, gridDim.x);
  const int row0 = (lin % gx) * 256, n0 = (lin / gx) * 256;
  const int tid = threadIdx.x;
  G8Ptrs P;
#pragma unroll
  for (int i = 0; i < 4; ++i) {
    int r, c; swz_rc(tid, i, r, c);
    P.a[i] = A + (size_t)(row0 + r) * K + c;
    P.b[i] = B + (size_t)(n0 + r) * K + c;
  }
  f32x4 acc[8][4] = {};
  g8_mainloop(P, K / 64, As, Bs, acc);
  const int lane = tid & 63, wid = tid >> 6;
  const int wr = wid >> 2, wc = wid & 3;
  const int fr = lane & 15, r0 = (lane >> 4) * 4;
  const int hc0 = (n0 + wc * 64) >> 1;
#pragma unroll
  for (int m = 0; m < 8; ++m)
#pragma unroll
    for (int k = 0; k < 2; ++k)
#pragma unroll
      for (int rr = 0; rr < 4; ++rr) {
        const int row = row0 + wr * 128 + m * 16 + r0 + rr;
        const int hcol = hc0 + k * 16 + fr;
        const float g = acc[m][2 * k][rr];
        const float u = acc[m][2 * k + 1][rr];
        H[(size_t)row * Nh + hcol] = (f16)(silu_f(g) * u);
      }
}

// shared down: plain f32 stores (runs before routed down's atomic accumulation)
__global__ __launch_bounds__(512, 2)
void g8_down(const f16* __restrict__ A, const f16* __restrict__ B,
             float* __restrict__ out, int gx, int N, int K) {
  __shared__ f16 As[2 * 16384], Bs[2 * 16384];
  const int lin = xcd_swz(blockIdx.x, gridDim.x);
  const int row0 = (lin % gx) * 256, n0 = (lin / gx) * 256;
  const int tid = threadIdx.x;
  G8Ptrs P;
#pragma unroll
  for (int i = 0; i < 4; ++i) {
    int r, c; swz_rc(tid, i, r, c);
    P.a[i] = A + (size_t)(row0 + r) * K + c;
    P.b[i] = B + (size_t)(n0 + r) * K + c;
  }
  f32x4 acc[8][4] = {};
  g8_mainloop(P, K / 64, As, Bs, acc);
  const int lane = tid & 63, wid = tid >> 6;
  const int wr = wid >> 2, wc = wid & 3;
  const int fr = lane & 15, r0 = (lane >> 4) * 4;
#pragma unroll
  for (int m = 0; m < 8; ++m)
#pragma unroll
    for (int n = 0; n < 4; ++n)
#pragma unroll
      for (int rr = 0; rr < 4; ++rr) {
        const int row = row0 + wr * 128 + m * 16 + r0 + rr;
        const int col = n0 + wc * 64 + n * 16 + fr;
        out[(size_t)row * N + col] = acc[m][n][rr];
      }
}

// routed gate|up + fused silu: A rows gathered per-lane from x16 via rowtok
// (scattered row-granular reads — measured equal to contiguous); per-expert
// interleaved B [2048][DM]; writes hr [rows][HR] directly.
__global__ __launch_bounds__(512, 2)
void g8_rgu(const f16* __restrict__ x16, const int* __restrict__ rowtok,
            const f16* __restrict__ Wgu, f16* __restrict__ hr,
            const int* __restrict__ seg) {
  __shared__ f16 As[2 * 16384], Bs[2 * 16384];
  const int e = blockIdx.z;
  const int row0 = seg[e] + blockIdx.y * 256;
  if (row0 >= seg[e + 1]) return;
  const int n0 = blockIdx.x * 256;
  const f16* Bbase = Wgu + (size_t)e * 2048 * DM;
  const int tid = threadIdx.x;
  G8Ptrs P;
#pragma unroll
  for (int i = 0; i < 4; ++i) {
    int r, c; swz_rc(tid, i, r, c);
    int tok = rowtok[row0 + r];
    if (tok < 0) tok = 0;   // pad rows: junk, discarded downstream
    P.a[i] = x16 + (size_t)tok * DM + c;
    P.b[i] = Bbase + (size_t)(n0 + r) * DM + c;
  }
  f32x4 acc[8][4] = {};
  g8_mainloop(P, DM / 64, As, Bs, acc);
  const int lane = tid & 63, wid = tid >> 6;
  const int wr = wid >> 2, wc = wid & 3;
  const int fr = lane & 15, r0 = (lane >> 4) * 4;
  const int hc0 = (n0 + wc * 64) >> 1;
#pragma unroll
  for (int m = 0; m < 8; ++m)
#pragma unroll
    for (int k = 0; k < 2; ++k)
#pragma unroll
      for (int rr = 0; rr < 4; ++rr) {
        const int row = row0 + wr * 128 + m * 16 + r0 + rr;
        const int hcol = hc0 + k * 16 + fr;
        const float g = acc[m][2 * k][rr];
        const float u = acc[m][2 * k + 1][rr];
        hr[(size_t)row * HR + hcol] = (f16)(silu_f(g) * u);
      }
}

// routed down: A=hr [rows][HR], per-expert B [DM][HR], gated atomicAdd scatter
__global__ __launch_bounds__(512, 2)
void g8_rdown(const f16* __restrict__ A, const f16* __restrict__ B,
              float* __restrict__ out, const int* __restrict__ seg,
              const int* __restrict__ rowtok, const float* __restrict__ rowgate) {
  __shared__ f16 As[2 * 16384], Bs[2 * 16384];
  const int e = blockIdx.z;
  const int row0 = seg[e] + blockIdx.y * 256;
  if (row0 >= seg[e + 1]) return;
  const int n0 = blockIdx.x * 256;
  const f16* Bbase = B + (size_t)e * DM * HR;
  const int tid = threadIdx.x;
  G8Ptrs P;
#pragma unroll
  for (int i = 0; i < 4; ++i) {
    int r, c; swz_rc(tid, i, r, c);
    P.a[i] = A + (size_t)(row0 + r) * HR + c;
    P.b[i] = Bbase + (size_t)(n0 + r) * HR + c;
  }
  f32x4 acc[8][4] = {};
  g8_mainloop(P, HR / 64, As, Bs, acc);
  const int lane = tid & 63, wid = tid >> 6;
  const int wr = wid >> 2, wc = wid & 3;
  const int fr = lane & 15, r0 = (lane >> 4) * 4;
#pragma unroll
  for (int m = 0; m < 8; ++m)
#pragma unroll
    for (int rr = 0; rr < 4; ++rr) {
      const int pos = row0 + wr * 128 + m * 16 + r0 + rr;
      const int tok = rowtok[pos];
      if (tok >= 0) {
        const float gw = rowgate[pos];
#pragma unroll
        for (int n = 0; n < 4; ++n) {
          const int col = n0 + wc * 64 + n * 16 + fr;
          atomicAdd(&out[(size_t)tok * DM + col], acc[m][n][rr] * gw);
        }
      }
    }
}

// ---------------- host ----------------

extern "C" void kernel_launch(void* const* d_in, const int* in_sizes, int n_in,
                              void* d_out, int out_size, void* d_ws, size_t ws_size,
                              hipStream_t stream) {
  const float* x  = (const float*)d_in[0];
  const float* wg = (const float*)d_in[1];
  const float* Wg = (const float*)d_in[2];
  const float* Wu = (const float*)d_in[3];
  const float* Wd = (const float*)d_in[4];
  const float* Sg = (const float*)d_in[5];
  const float* Su = (const float*)d_in[6];
  const float* Sd = (const float*)d_in[7];
  float* out = (float*)d_out;

  char* p = (char*)d_ws;
  auto take = [&](size_t b) { char* q = p; p += (b + 255) & ~(size_t)255; return q; };
  float* importance = (float*)take(32);
  int*   cnt        = (int*)take(32);
  int*   cursor     = (int*)take(32);
  int*   seg        = (int*)take(64);
  int*   rowtok     = (int*)take((size_t)ROWS_MAX * 4);
  float* rowgate    = (float*)take((size_t)ROWS_MAX * 4);
  float* gateW      = (float*)take((size_t)NTOK * 2 * 4);
  int*   gateI      = (int*)take((size_t)NTOK * 2 * 4);
  f16* x16   = (f16*)take((size_t)NTOK * DM * 2);
  f16* SguI  = (f16*)take((size_t)2 * HS * DM * 2);       // [16384][2048] g/u 16-interleaved
  f16* SdT   = (f16*)take((size_t)DM * HS * 2);           // [2048][8192]
  f16* WguI  = (f16*)take((size_t)NEXP * 2048 * DM * 2);  // [e][2048][2048] interleaved
  f16* WdT   = (f16*)take((size_t)NEXP * DM * HR * 2);    // [e][2048][1024]
  f16* hbuf  = (f16*)take((size_t)NTOK * HS * 2);         // h for all 8192 tokens (128 MB)
  f16* hr    = (f16*)take((size_t)ROWS_MAX * HR * 2);     // routed h
  if ((size_t)(p - (char*)d_ws) > ws_size) return;  // ws too small -> loud fail

  hipMemsetAsync(importance, 0, 768, stream);                 // importance+cnt+cursor
  hipMemsetAsync(rowtok, 0xFF, (size_t)ROWS_MAX * 4, stream); // -1

  // gate (+ fused x->f16), then routing metadata
  gate_kernel<<<NTOK / 32, 256, 0, stream>>>(x, wg, x16, gateW, gateI, importance, cnt);
  scan_kernel<<<1, 64, 0, stream>>>(cnt, seg, cursor, importance, out + (size_t)NTOK * DM);
  scatter_kernel<<<NTOK / 256, 256, 0, stream>>>(gateW, gateI, seg, cursor, rowtok, rowgate);

  // all 6 weight transposes in one dispatch (6 x 16384 tiles)
  conv_all_kernel<<<6 * 16384, dim3(32, 8), 0, stream>>>(Sg, Su, Sd, Wg, Wu, Wd,
                                                         SguI, SdT, WguI, WdT);

  // routed gate|up (+silu fused)  [256-padded segments; empty tiles early-exit]
  g8_rgu<<<dim3(8, 33, NEXP), 512, 0, stream>>>(x16, rowtok, WguI, hr, seg);

  // shared expert: one gu dispatch (M=8192), one down dispatch (plain stores)
  g8_gu<<<32 * 64, 512, 0, stream>>>(x16, SguI, hbuf, 32, HS, DM);
  g8_down<<<32 * 8, 512, 0, stream>>>(hbuf, SdT, out, 32, DM, HS);

  // routed down accumulates on top of the shared result (stream-ordered)
  g8_rdown<<<dim3(8, 33, NEXP), 512, 0, stream>>>(hr, WdT, out, seg, rowtok, rowgate);
}